// Round 9
// baseline (277.044 us; speedup 1.0000x reference)
//
#include <hip/hip_runtime.h>
#include <math.h>

#define P_N 524288
#define NFRAMES 100
#define RESO_ 256
#define CHAN_ 64
#define NFREQ 10

// Transposed layout: T[(f*3+pl)][t][x][c] ; c contiguous
#define TROW   (RESO_ * CHAN_)          // 16384 floats per t-row
#define TPLANE (NFRAMES * TROW)         // 1,638,400 floats per plane

#define NSUBS 8                         // independent sort blocks
#define SUBSZ (P_N / NSUBS)             // 65536 points per sub
#define CHUNKS (SUBSZ / 32)             // 2048 chunks of 32 per sub
#define NKEY (NFRAMES * 128)            // key = t*128 + (x0(cx)>>1) -> 12800
#define NTRB  (3 * 3 * NFRAMES * 4)     // 3600 transpose blocks

// ---------------- fused prep: 8 per-sub LDS counting-sorts + transpose ----
// Sort key = (t, x0(cx)/2): waves then see consecutive points sharing the
// same T column on the 3 cx-planes -> TCP coalescing + L1 reuse (R9).
template <bool WXS>
__global__ __launch_bounds__(256) void prep3_k(const float* __restrict__ f0,
                                               const float* __restrict__ f1,
                                               const float* __restrict__ f2,
                                               float* __restrict__ T,
                                               const float* __restrict__ xin,
                                               int* __restrict__ perm,
                                               float4* __restrict__ xs4) {
  __shared__ unsigned smem[NKEY];        // 51.2 KB; re-used as transpose tile

  if (blockIdx.x < NSUBS) {
    if (perm == nullptr) return;         // transpose-only tier
    const int s = blockIdx.x;
    const float4* __restrict__ x4 = (const float4*)xin;
    for (int i = threadIdx.x; i < NKEY; i += 256) smem[i] = 0;
    __syncthreads();
    // phase A: histogram of (t, x0/2) within this sub
    for (int i = threadIdx.x; i < SUBSZ; i += 256) {
      float4 v = x4[(size_t)s * SUBSZ + i];
      int t = min(max((int)v.w, 0), NFRAMES - 1);
      int x0 = min(max((int)floorf(v.x * 255.0f), 0), 254);
      atomicAdd(&smem[t * 128 + (x0 >> 1)], 1u);
    }
    __syncthreads();
    // phase B: exclusive scan (256 x 50 serial + partial scan)
    {
      const int tid = threadIdx.x;
      const int CH = NKEY / 256;         // 50
      unsigned loc = 0;
      unsigned vals[CH];
      #pragma unroll
      for (int i = 0; i < CH; i++) { vals[i] = smem[tid * CH + i]; }
      for (int i = 0; i < CH; i++) { unsigned v = vals[i]; vals[i] = loc; loc += v; }
      __syncthreads();
      __shared__ unsigned part[257];
      part[tid] = loc;
      __syncthreads();
      if (tid == 0) {
        unsigned r = 0;
        for (int jj = 0; jj < 256; jj++) { unsigned v = part[jj]; part[jj] = r; r += v; }
      }
      __syncthreads();
      for (int i = 0; i < CH; i++) smem[tid * CH + i] = part[tid] + vals[i];
      __syncthreads();
    }
    // phase C: scatter perm (+ sorted coords)
    for (int i = threadIdx.x; i < SUBSZ; i += 256) {
      float4 v = x4[(size_t)s * SUBSZ + i];
      int t = min(max((int)v.w, 0), NFRAMES - 1);
      int x0 = min(max((int)floorf(v.x * 255.0f), 0), 254);
      int pos = s * SUBSZ + (int)atomicAdd(&smem[t * 128 + (x0 >> 1)], 1u);
      perm[pos] = s * SUBSZ + i;
      if (WXS) xs4[pos] = v;
    }
    return;
  }

  // ---- transpose blocks ----
  float (*tile)[65] = (float(*)[65])smem;    // 64*65*4 = 16.6 KB of smem
  int b = blockIdx.x - NSUBS;
  int xblk = b & 3; b >>= 2;                 // 4 x-tiles of 64
  int t = b % NFRAMES; b /= NFRAMES;
  int pl = b % 3; int f = b / 3;
  const float* src = (f == 0 ? f0 : (f == 1 ? f1 : f2)) + (size_t)pl * CHAN_ * NFRAMES * RESO_;
  int lane = threadIdx.x & 63;
  int w = threadIdx.x >> 6;
  #pragma unroll
  for (int c = 0; c < 16; c++) {
    int cc = w * 16 + c;
    tile[cc][lane] = src[(size_t)cc * (NFRAMES * RESO_) + (size_t)t * RESO_ + xblk * 64 + lane];
  }
  __syncthreads();
  float* dst = T + ((size_t)(f * 3 + pl) * NFRAMES + t) * TROW + (size_t)(xblk * 64) * CHAN_;
  #pragma unroll
  for (int i = 0; i < 16; i++) {
    int xx = w * 16 + i;
    dst[(size_t)xx * CHAN_ + lane] = tile[lane][xx];
  }
}

__device__ __forceinline__ float hw_sin_rev(float rev) {
  float r, s;
  asm("v_fract_f32 %0, %1" : "=v"(r) : "v"(rev));
  asm("v_sin_f32 %0, %1" : "=v"(s) : "v"(r));
  return s;
}

// STAGE: weights + 3 distinct 32-bit column offsets, issue 18 row loads.
#define STAGEM(V0, V1, WX, WY3, C)                                           \
  {                                                                          \
    float tn = (C).w * (1.0f / 99.0f);                                       \
    float gy = 2.0f * tn - 1.0f;                                             \
    float iy = ((gy + 1.0f) * 0.5f) * 99.0f;                                 \
    float y0f = floorf(iy);                                                  \
    float wy1 = iy - y0f;                                                    \
    int row; float wy;                                                       \
    if (wy1 > 0.5f) { row = (int)y0f + 1; wy = wy1; }                        \
    else            { row = (int)y0f;     wy = 1.0f - wy1; }                 \
    row = min(max(row, 0), NFRAMES - 1);                                     \
    (WY3) = wy * wy * wy;                                                    \
    const unsigned rowbyte = ((unsigned)row << 16) + ((unsigned)sl << 4);    \
    unsigned cb0, cb1, cb2;                                                  \
    { float gx = 2.0f * (C).x - 1.0f; float ix = ((gx + 1.0f) * 0.5f) * 255.0f; \
      float x0f = floorf(ix); (WX)[0] = ix - x0f;                            \
      cb0 = rowbyte + ((unsigned)(int)x0f << 8); }                           \
    { float gx = 2.0f * (C).y - 1.0f; float ix = ((gx + 1.0f) * 0.5f) * 255.0f; \
      float x0f = floorf(ix); (WX)[1] = ix - x0f;                            \
      cb1 = rowbyte + ((unsigned)(int)x0f << 8); }                           \
    { float gx = 2.0f * (C).z - 1.0f; float ix = ((gx + 1.0f) * 0.5f) * 255.0f; \
      float x0f = floorf(ix); (WX)[2] = ix - x0f;                            \
      cb2 = rowbyte + ((unsigned)(int)x0f << 8); }                           \
    _Pragma("unroll")                                                        \
    for (int ss = 0; ss < 9; ss++) {                                         \
      const char* bp = Tb + (size_t)ss * ((size_t)TPLANE * 4);               \
      unsigned cb = (ss % 3 == 0) ? cb0 : (ss % 3 == 1) ? cb1 : cb2;         \
      (V0)[ss] = *(const float4*)(bp + cb);                                  \
      (V1)[ss] = *(const float4*)(bp + cb + 256);                            \
    }                                                                        \
  }

// CONSUME: lerp+product+16-group reduce+PE+store for 4 points (KIDX literal)
#define CONSUMEM(V0, V1, WX, WY3, C, KIDX)                                   \
  {                                                                          \
    float dsum[3];                                                           \
    _Pragma("unroll")                                                        \
    for (int f = 0; f < 3; f++) {                                            \
      float prx, pry, prz, prw;                                              \
      _Pragma("unroll")                                                      \
      for (int pl = 0; pl < 3; pl++) {                                       \
        int ss = f * 3 + pl;                                                 \
        float w1 = (WX)[pl];                                                 \
        float sx = fmaf(w1, (V1)[ss].x - (V0)[ss].x, (V0)[ss].x);            \
        float sy = fmaf(w1, (V1)[ss].y - (V0)[ss].y, (V0)[ss].y);            \
        float sz = fmaf(w1, (V1)[ss].z - (V0)[ss].z, (V0)[ss].z);            \
        float sw = fmaf(w1, (V1)[ss].w - (V0)[ss].w, (V0)[ss].w);            \
        if (pl == 0) { prx = sx; pry = sy; prz = sz; prw = sw; }             \
        else         { prx *= sx; pry *= sy; prz *= sz; prw *= sw; }         \
      }                                                                      \
      float r = ((prx + pry) + (prz + prw)) * (WY3);                         \
      _Pragma("unroll")                                                      \
      for (int m = 8; m > 0; m >>= 1) r += __shfl_xor(r, m, 64);             \
      dsum[f] = r;                                                           \
    }                                                                        \
    float px = (C).x + dsum[0];                                              \
    float py = (C).y + dsum[1];                                              \
    float pz = (C).z + dsum[2];                                              \
    _Pragma("unroll")                                                        \
    for (int q2 = 0; q2 < 4; q2++) {                                         \
      float qx = __shfl(px, q2 * 16, 64);                                    \
      float qy = __shfl(py, q2 * 16, 64);                                    \
      float qz = __shfl(pz, q2 * 16, 64);                                    \
      int pq = __shfl(permv, (KIDX) * 4 + q2, 64);                           \
      float pd = (dd == 0) ? qx : (dd == 1) ? qy : qz;                       \
      float val = hw_sin_rev(pd * scale * inv2pi + cosoff);                  \
      if (lane == 0) val = qx;                                               \
      else if (lane == 1) val = qy;                                          \
      else if (lane == 2) val = qz;                                          \
      if (lane < 63)                                                         \
        __builtin_nontemporal_store(val, &out[(size_t)pq * 63 + lane]);      \
    }                                                                        \
  }

// 4 points/iter; batch of 18 row-loads fenced by sched_barrier(0).
// Wave owns 32 consecutive points of its sub's (t,x)-sorted order.
__global__ __launch_bounds__(256, 3) void sample4p_k(const float4* __restrict__ xs4,
                                                     const float* __restrict__ T,
                                                     const int* __restrict__ perm,
                                                     float* __restrict__ out) {
  const int lane = threadIdx.x & 63;
  const int g = lane >> 4;
  const int sl = lane & 15;
  const int b = blockIdx.x;         // 4096 blocks
  const int wix = (b >> 3) * 4 + (threadIdx.x >> 6);   // 0..2047
  const int q = (b & 7) * (CHUNKS / 8) + (wix >> 3);   // chunk 0..2047 (~t,x)
  const int s = wix & 7;                               // sub 0..7
  const int base = s * SUBSZ + q * 32;                 // 32 points per wave

  const int j = (lane >= 3) ? (lane - 3) : 0;
  const int fq = j / 6;
  const int rr = j - fq * 6;
  const int isc = rr / 3;
  const int dd = rr - isc * 3;
  const float scale = (float)(1 << fq);
  const float cosoff = isc ? 0.25f : 0.0f;
  const float inv2pi = 0.15915493667125702f;

  const char* Tb = (const char*)T;
  const int permv = perm[base + (lane & 31)];

  float4 c = xs4[base + g];

  #pragma unroll 2
  for (int k = 0; k < 8; k++) {
    float4 v0[9], v1[9];
    float wx[3], wy3;
    STAGEM(v0, v1, wx, wy3, c);
    float4 c_nxt = c;
    if (k < 7) c_nxt = xs4[base + (k + 1) * 4 + g];
    __builtin_amdgcn_sched_barrier(0);     // pin the 19-load batch above
    CONSUMEM(v0, v1, wx, wy3, c, k);
    c = c_nxt;
  }
}

// ---- non-pipelined sorted variant (perm but no xs tier) ----
__global__ __launch_bounds__(256) void sample4s_k(const float* __restrict__ xin,
                                                  const float* __restrict__ T,
                                                  const int* __restrict__ perm,
                                                  float* __restrict__ out) {
  const int lane = threadIdx.x & 63;
  const int g = lane >> 4;
  const int sl = lane & 15;
  const int b = blockIdx.x;
  const int wix = (b >> 3) * 4 + (threadIdx.x >> 6);
  const int q = (b & 7) * (CHUNKS / 8) + (wix >> 3);
  const int s = wix & 7;
  const int base = s * SUBSZ + q * 32;

  const int j = (lane >= 3) ? (lane - 3) : 0;
  const int fq = j / 6;
  const int rr = j - fq * 6;
  const int isc = rr / 3;
  const int dd = rr - isc * 3;
  const float scale = (float)(1 << fq);
  const float cosoff = isc ? 0.25f : 0.0f;
  const float inv2pi = 0.15915493667125702f;

  const char* Tb = (const char*)T;
  const float4* __restrict__ x4 = (const float4*)xin;
  const int permv = perm[base + (lane & 31)];

  float4 c = x4[__shfl(permv, g, 64)];

  #pragma unroll 2
  for (int k = 0; k < 8; k++) {
    float4 v0[9], v1[9];
    float wx[3], wy3;
    STAGEM(v0, v1, wx, wy3, c);
    float4 c_nxt = c;
    if (k < 7) c_nxt = x4[__shfl(permv, (k + 1) * 4 + g, 64)];
    __builtin_amdgcn_sched_barrier(0);
    CONSUMEM(v0, v1, wx, wy3, c, k);
    c = c_nxt;
  }
}

// ---- unsorted variant (ws fits T only): 2-pt/wave, float2 channel pairs ----
__global__ __launch_bounds__(256) void sample2_k(const float* __restrict__ xin,
                                                 const float* __restrict__ T,
                                                 float* __restrict__ out) {
  const int lane = threadIdx.x & 63;
  const int half = lane >> 5;
  const int l = lane & 31;
  const int wave = blockIdx.x * 4 + (threadIdx.x >> 6);
  const int nW = gridDim.x * 4;
  const int j = (lane >= 3) ? (lane - 3) : 0;
  const int fq = j / 6;
  const int rr = j - fq * 6;
  const int isc = rr / 3;
  const int dd = rr - isc * 3;
  const float scale = (float)(1 << fq);
  const float cosoff = isc ? 0.25f : 0.0f;
  const float inv2pi = 0.15915493667125702f;
  const float4* __restrict__ x4 = (const float4*)xin;

  for (int base = wave * 2; base < P_N; base += nW * 2) {
    const int p = base + half;
    float4 c = x4[p];
    float tn = c.w / 99.0f;
    float gy = 2.0f * tn - 1.0f;
    float iy = ((gy + 1.0f) * 0.5f) * 99.0f;
    float y0f = floorf(iy);
    float wy1 = iy - y0f;
    int row; float wy;
    if (wy1 > 0.5f) { row = (int)y0f + 1; wy = wy1; }
    else            { row = (int)y0f;     wy = 1.0f - wy1; }
    row = min(max(row, 0), NFRAMES - 1);
    const int rowoff = row * TROW;
    float dsum[3];
    float crd[3] = {c.x, c.y, c.z};
    #pragma unroll
    for (int f = 0; f < 3; f++) {
      float prx, pry;
      #pragma unroll
      for (int pl = 0; pl < 3; pl++) {
        float gx = 2.0f * crd[pl] - 1.0f;
        float ix = ((gx + 1.0f) * 0.5f) * 255.0f;
        float x0f = floorf(ix);
        float wx1 = ix - x0f;
        float wx0 = 1.0f - wx1;
        int x0 = (int)x0f;
        const float2* rp = (const float2*)(T + (size_t)(f * 3 + pl) * TPLANE
                                             + (size_t)(rowoff + x0 * CHAN_));
        float2 v0 = rp[l];
        float2 v1 = rp[l + 32];
        float sx = (v0.x * wx0 + v1.x * wx1) * wy;
        float sy = (v0.y * wx0 + v1.y * wx1) * wy;
        if (pl == 0) { prx = sx; pry = sy; }
        else         { prx *= sx; pry *= sy; }
      }
      float r = prx + pry;
      #pragma unroll
      for (int m = 16; m > 0; m >>= 1) r += __shfl_xor(r, m, 64);
      dsum[f] = r;
    }
    float px = c.x + dsum[0];
    float py = c.y + dsum[1];
    float pz = c.z + dsum[2];
    #pragma unroll
    for (int qq = 0; qq < 2; qq++) {
      float qx = __shfl(px, qq * 32, 64);
      float qy = __shfl(py, qq * 32, 64);
      float qz = __shfl(pz, qq * 32, 64);
      float pd = (dd == 0) ? qx : (dd == 1) ? qy : qz;
      float val = hw_sin_rev(pd * scale * inv2pi + cosoff);
      if (lane == 0) val = qx;
      else if (lane == 1) val = qy;
      else if (lane == 2) val = qz;
      if (lane < 63) out[(size_t)(base + qq) * 63 + lane] = val;
    }
  }
}

// ---- fallback (no usable ws): direct-layout sampler ----
__global__ __launch_bounds__(256) void sample_fb_k(const float* __restrict__ xin,
                                                   const float* __restrict__ f0,
                                                   const float* __restrict__ f1,
                                                   const float* __restrict__ f2,
                                                   float* __restrict__ out) {
  const int lane = threadIdx.x & 63;
  int wave = blockIdx.x * 4 + (threadIdx.x >> 6);
  const int nW = gridDim.x * 4;
  for (int p = wave; p < P_N; p += nW) {
    float cx = xin[(size_t)p * 4 + 0];
    float cy = xin[(size_t)p * 4 + 1];
    float cz = xin[(size_t)p * 4 + 2];
    float ct = xin[(size_t)p * 4 + 3];
    float tn = ct / 99.0f;
    float gy = 2.0f * tn - 1.0f;
    float iy = ((gy + 1.0f) * 0.5f) * 99.0f;
    float y0f = floorf(iy);
    float wy1 = iy - y0f;
    float wy0 = 1.0f - wy1;
    int y0 = (int)y0f, y1 = y0 + 1;
    bool y0in = (unsigned)y0 < (unsigned)NFRAMES;
    bool y1in = (unsigned)y1 < (unsigned)NFRAMES;
    int y0c = min(max(y0, 0), NFRAMES - 1);
    int y1c = min(max(y1, 0), NFRAMES - 1);
    float d[3];
    #pragma unroll
    for (int f = 0; f < 3; f++) {
      float prodc;
      #pragma unroll
      for (int pl = 0; pl < 3; pl++) {
        float coord = (pl == 0) ? cx : (pl == 1) ? cy : cz;
        float gx = 2.0f * coord - 1.0f;
        float ix = ((gx + 1.0f) * 0.5f) * 255.0f;
        float x0f = floorf(ix);
        float wx1 = ix - x0f;
        float wx0 = 1.0f - wx1;
        int x0 = (int)x0f, x1 = x0 + 1;
        int x0c = min(max(x0, 0), RESO_ - 1);
        int x1c = min(max(x1, 0), RESO_ - 1);
        const float* ff = (f == 0) ? f0 : (f == 1) ? f1 : f2;
        const float* bse = ff + ((size_t)pl * CHAN_ + lane) * (NFRAMES * RESO_);
        float v00 = y0in ? bse[(size_t)y0c * RESO_ + x0c] : 0.0f;
        float v01 = y0in ? bse[(size_t)y0c * RESO_ + x1c] : 0.0f;
        float v10 = y1in ? bse[(size_t)y1c * RESO_ + x0c] : 0.0f;
        float v11 = y1in ? bse[(size_t)y1c * RESO_ + x1c] : 0.0f;
        float ss2 = v00 * (wy0 * wx0) + v01 * (wy0 * wx1) + v10 * (wy1 * wx0) + v11 * (wy1 * wx1);
        prodc = (pl == 0) ? ss2 : prodc * ss2;
      }
      float sum = prodc;
      #pragma unroll
      for (int o = 32; o > 0; o >>= 1) sum += __shfl_xor(sum, o, 64);
      d[f] = sum;
    }
    float p0 = cx + d[0], p1 = cy + d[1], p2 = cz + d[2];
    if (lane < 63) {
      float val;
      if (lane == 0) val = p0;
      else if (lane == 1) val = p1;
      else if (lane == 2) val = p2;
      else {
        int jj = lane - 3;
        int fq2 = jj / 6;
        int r2 = jj - fq2 * 6;
        int s2 = r2 / 3;
        int d2 = r2 - s2 * 3;
        float pd = (d2 == 0) ? p0 : (d2 == 1) ? p1 : p2;
        float ang = pd * (float)(1 << fq2);
        val = (s2 == 0) ? sinf(ang) : cosf(ang);
      }
      out[(size_t)p * 63 + lane] = val;
    }
  }
}

extern "C" void kernel_launch(void* const* d_in, const int* in_sizes, int n_in,
                              void* d_out, int out_size, void* d_ws, size_t ws_size,
                              hipStream_t stream) {
  const float* x  = (const float*)d_in[0];
  const float* f0 = (const float*)d_in[1];
  const float* f1 = (const float*)d_in[2];
  const float* f2 = (const float*)d_in[3];
  float* out = (float*)d_out;

  const size_t szT    = (size_t)9 * TPLANE * sizeof(float);     // ~59 MB
  const size_t szPerm = (size_t)P_N * sizeof(int);              // 2 MB
  const size_t szXs   = (size_t)P_N * sizeof(float4);           // 8 MB

  if (ws_size >= szT + szPerm + szXs) {
    float* T    = (float*)d_ws;
    int* perm   = (int*)((char*)d_ws + szT);
    float4* xs4 = (float4*)((char*)d_ws + szT + szPerm);
    prep3_k<true><<<dim3(NSUBS + NTRB), dim3(256), 0, stream>>>(f0, f1, f2, T, x, perm, xs4);
    sample4p_k<<<dim3(4096), dim3(256), 0, stream>>>(xs4, T, perm, out);
  } else if (ws_size >= szT + szPerm) {
    float* T  = (float*)d_ws;
    int* perm = (int*)((char*)d_ws + szT);
    prep3_k<false><<<dim3(NSUBS + NTRB), dim3(256), 0, stream>>>(f0, f1, f2, T, x, perm, nullptr);
    sample4s_k<<<dim3(4096), dim3(256), 0, stream>>>(x, T, perm, out);
  } else if (ws_size >= szT) {
    float* T = (float*)d_ws;
    prep3_k<false><<<dim3(NSUBS + NTRB), dim3(256), 0, stream>>>(f0, f1, f2, T, x, nullptr, nullptr);
    sample2_k<<<dim3(4096), dim3(256), 0, stream>>>(x, T, out);
  } else {
    sample_fb_k<<<dim3(8192), dim3(256), 0, stream>>>(x, f0, f1, f2, out);
  }
}

// Round 10
// 138.565 us; speedup vs baseline: 1.9994x; 1.9994x over previous
//
#include <hip/hip_runtime.h>
#include <math.h>

#define P_N 524288
#define NFRAMES 100
#define RESO_ 256
#define CHAN_ 64
#define NFREQ 10

// Transposed layout: T[(f*3+pl)][t][x][c] ; c contiguous
#define TROW   (RESO_ * CHAN_)          // 16384 floats per t-row
#define TPLANE (NFRAMES * TROW)         // 1,638,400 floats per plane

#define NSUBS 64                        // independent sort blocks (R9 lesson:
#define SUBSZ (P_N / NSUBS)             //   8 blocks serialized -> keep 64)
#define CHUNKS (SUBSZ / 32)             // 256 chunks of 32 per sub
#define NKEY (NFRAMES * 128)            // key = t*128 + (x0(cx)>>1) -> 12800
#define NTRB  (3 * 3 * NFRAMES * 4)     // 3600 transpose blocks

// ---------------- fused prep: 64 per-sub LDS counting-sorts + transpose ----
// Sort key = (t, x0(cx)/2): waves see consecutive points sharing the same T
// column on the 3 cx-planes -> TCP line merging + L1 reuse.
template <bool WXS>
__global__ __launch_bounds__(256) void prep4_k(const float* __restrict__ f0,
                                               const float* __restrict__ f1,
                                               const float* __restrict__ f2,
                                               float* __restrict__ T,
                                               const float* __restrict__ xin,
                                               int* __restrict__ perm,
                                               float4* __restrict__ xs4) {
  __shared__ unsigned smem[NKEY];        // 51.2 KB; re-used as transpose tile
  __shared__ unsigned part[257];

  if (blockIdx.x < NSUBS) {
    if (perm == nullptr) return;         // transpose-only tier
    const int s = blockIdx.x;
    const float4* __restrict__ x4 = (const float4*)xin;
    for (int i = threadIdx.x; i < NKEY; i += 256) smem[i] = 0;
    __syncthreads();
    // phase A: histogram of (t, x0/2) within this sub (32 iter)
    for (int i = threadIdx.x; i < SUBSZ; i += 256) {
      float4 v = x4[(size_t)s * SUBSZ + i];
      int t = min(max((int)v.w, 0), NFRAMES - 1);
      int x0 = min(max((int)floorf(v.x * 255.0f), 0), 254);
      atomicAdd(&smem[t * 128 + (x0 >> 1)], 1u);
    }
    __syncthreads();
    // phase B: exclusive scan (256 x 50 + partials)
    {
      const int tid = threadIdx.x;
      const int CH = NKEY / 256;         // 50
      unsigned vals[CH];
      unsigned loc = 0;
      #pragma unroll
      for (int i = 0; i < CH; i++) vals[i] = smem[tid * CH + i];
      for (int i = 0; i < CH; i++) { unsigned v = vals[i]; vals[i] = loc; loc += v; }
      part[tid] = loc;
      __syncthreads();
      if (tid == 0) {
        unsigned r = 0;
        for (int jj = 0; jj < 256; jj++) { unsigned v = part[jj]; part[jj] = r; r += v; }
      }
      __syncthreads();
      for (int i = 0; i < CH; i++) smem[tid * CH + i] = part[tid] + vals[i];
      __syncthreads();
    }
    // phase C: scatter perm (+ sorted coords) (32 iter)
    for (int i = threadIdx.x; i < SUBSZ; i += 256) {
      float4 v = x4[(size_t)s * SUBSZ + i];
      int t = min(max((int)v.w, 0), NFRAMES - 1);
      int x0 = min(max((int)floorf(v.x * 255.0f), 0), 254);
      int pos = s * SUBSZ + (int)atomicAdd(&smem[t * 128 + (x0 >> 1)], 1u);
      perm[pos] = s * SUBSZ + i;
      if (WXS) xs4[pos] = v;
    }
    return;
  }

  // ---- transpose blocks ----
  float (*tile)[65] = (float(*)[65])smem;
  int b = blockIdx.x - NSUBS;
  int xblk = b & 3; b >>= 2;                 // 4 x-tiles of 64
  int t = b % NFRAMES; b /= NFRAMES;
  int pl = b % 3; int f = b / 3;
  const float* src = (f == 0 ? f0 : (f == 1 ? f1 : f2)) + (size_t)pl * CHAN_ * NFRAMES * RESO_;
  int lane = threadIdx.x & 63;
  int w = threadIdx.x >> 6;
  #pragma unroll
  for (int c = 0; c < 16; c++) {
    int cc = w * 16 + c;
    tile[cc][lane] = src[(size_t)cc * (NFRAMES * RESO_) + (size_t)t * RESO_ + xblk * 64 + lane];
  }
  __syncthreads();
  float* dst = T + ((size_t)(f * 3 + pl) * NFRAMES + t) * TROW + (size_t)(xblk * 64) * CHAN_;
  #pragma unroll
  for (int i = 0; i < 16; i++) {
    int xx = w * 16 + i;
    dst[(size_t)xx * CHAN_ + lane] = tile[lane][xx];
  }
}

__device__ __forceinline__ float hw_sin_rev(float rev) {
  float r, s;
  asm("v_fract_f32 %0, %1" : "=v"(r) : "v"(rev));
  asm("v_sin_f32 %0, %1" : "=v"(s) : "v"(r));
  return s;
}

// STAGE: weights + 3 distinct 32-bit column offsets, issue 18 row loads.
#define STAGEM(V0, V1, WX, WY3, C)                                           \
  {                                                                          \
    float tn = (C).w * (1.0f / 99.0f);                                       \
    float gy = 2.0f * tn - 1.0f;                                             \
    float iy = ((gy + 1.0f) * 0.5f) * 99.0f;                                 \
    float y0f = floorf(iy);                                                  \
    float wy1 = iy - y0f;                                                    \
    int row; float wy;                                                       \
    if (wy1 > 0.5f) { row = (int)y0f + 1; wy = wy1; }                        \
    else            { row = (int)y0f;     wy = 1.0f - wy1; }                 \
    row = min(max(row, 0), NFRAMES - 1);                                     \
    (WY3) = wy * wy * wy;                                                    \
    const unsigned rowbyte = ((unsigned)row << 16) + ((unsigned)sl << 4);    \
    unsigned cb0, cb1, cb2;                                                  \
    { float gx = 2.0f * (C).x - 1.0f; float ix = ((gx + 1.0f) * 0.5f) * 255.0f; \
      float x0f = floorf(ix); (WX)[0] = ix - x0f;                            \
      cb0 = rowbyte + ((unsigned)(int)x0f << 8); }                           \
    { float gx = 2.0f * (C).y - 1.0f; float ix = ((gx + 1.0f) * 0.5f) * 255.0f; \
      float x0f = floorf(ix); (WX)[1] = ix - x0f;                            \
      cb1 = rowbyte + ((unsigned)(int)x0f << 8); }                           \
    { float gx = 2.0f * (C).z - 1.0f; float ix = ((gx + 1.0f) * 0.5f) * 255.0f; \
      float x0f = floorf(ix); (WX)[2] = ix - x0f;                            \
      cb2 = rowbyte + ((unsigned)(int)x0f << 8); }                           \
    _Pragma("unroll")                                                        \
    for (int ss = 0; ss < 9; ss++) {                                         \
      const char* bp = Tb + (size_t)ss * ((size_t)TPLANE * 4);               \
      unsigned cb = (ss % 3 == 0) ? cb0 : (ss % 3 == 1) ? cb1 : cb2;         \
      (V0)[ss] = *(const float4*)(bp + cb);                                  \
      (V1)[ss] = *(const float4*)(bp + cb + 256);                            \
    }                                                                        \
  }

// CONSUME: lerp+product+16-group reduce+PE+store for 4 points (KIDX literal)
#define CONSUMEM(V0, V1, WX, WY3, C, KIDX)                                   \
  {                                                                          \
    float dsum[3];                                                           \
    _Pragma("unroll")                                                        \
    for (int f = 0; f < 3; f++) {                                            \
      float prx, pry, prz, prw;                                              \
      _Pragma("unroll")                                                      \
      for (int pl = 0; pl < 3; pl++) {                                       \
        int ss = f * 3 + pl;                                                 \
        float w1 = (WX)[pl];                                                 \
        float sx = fmaf(w1, (V1)[ss].x - (V0)[ss].x, (V0)[ss].x);            \
        float sy = fmaf(w1, (V1)[ss].y - (V0)[ss].y, (V0)[ss].y);            \
        float sz = fmaf(w1, (V1)[ss].z - (V0)[ss].z, (V0)[ss].z);            \
        float sw = fmaf(w1, (V1)[ss].w - (V0)[ss].w, (V0)[ss].w);            \
        if (pl == 0) { prx = sx; pry = sy; prz = sz; prw = sw; }             \
        else         { prx *= sx; pry *= sy; prz *= sz; prw *= sw; }         \
      }                                                                      \
      float r = ((prx + pry) + (prz + prw)) * (WY3);                         \
      _Pragma("unroll")                                                      \
      for (int m = 8; m > 0; m >>= 1) r += __shfl_xor(r, m, 64);             \
      dsum[f] = r;                                                           \
    }                                                                        \
    float px = (C).x + dsum[0];                                              \
    float py = (C).y + dsum[1];                                              \
    float pz = (C).z + dsum[2];                                              \
    _Pragma("unroll")                                                        \
    for (int q2 = 0; q2 < 4; q2++) {                                         \
      float qx = __shfl(px, q2 * 16, 64);                                    \
      float qy = __shfl(py, q2 * 16, 64);                                    \
      float qz = __shfl(pz, q2 * 16, 64);                                    \
      int pq = __shfl(permv, (KIDX) * 4 + q2, 64);                           \
      float pd = (dd == 0) ? qx : (dd == 1) ? qy : qz;                       \
      float val = hw_sin_rev(pd * scale * inv2pi + cosoff);                  \
      if (lane == 0) val = qx;                                               \
      else if (lane == 1) val = qy;                                          \
      else if (lane == 2) val = qz;                                          \
      if (lane < 63)                                                         \
        __builtin_nontemporal_store(val, &out[(size_t)pq * 63 + lane]);      \
    }                                                                        \
  }

// 4 points/iter; batch of 18 row-loads fenced by sched_barrier(0).
// Wave owns 32 consecutive points of its sub's (t,x)-sorted order;
// same within-sub chunk index (~same t) lands on the same XCD.
__global__ __launch_bounds__(256, 3) void sample4p_k(const float4* __restrict__ xs4,
                                                     const float* __restrict__ T,
                                                     const int* __restrict__ perm,
                                                     float* __restrict__ out) {
  const int lane = threadIdx.x & 63;
  const int g = lane >> 4;
  const int sl = lane & 15;
  const int b = blockIdx.x;         // 4096 blocks
  const int wix = (b >> 3) * 4 + (threadIdx.x >> 6);   // 0..2047 within XCD
  const int q = (b & 7) * 32 + (wix >> 6);             // chunk 0..255 (~t,x)
  const int s = wix & 63;                              // sub 0..63
  const int base = s * SUBSZ + q * 32;                 // 32 points per wave

  const int j = (lane >= 3) ? (lane - 3) : 0;
  const int fq = j / 6;
  const int rr = j - fq * 6;
  const int isc = rr / 3;
  const int dd = rr - isc * 3;
  const float scale = (float)(1 << fq);
  const float cosoff = isc ? 0.25f : 0.0f;
  const float inv2pi = 0.15915493667125702f;

  const char* Tb = (const char*)T;
  const int permv = perm[base + (lane & 31)];

  float4 c = xs4[base + g];

  #pragma unroll 2
  for (int k = 0; k < 8; k++) {
    float4 v0[9], v1[9];
    float wx[3], wy3;
    STAGEM(v0, v1, wx, wy3, c);
    float4 c_nxt = c;
    if (k < 7) c_nxt = xs4[base + (k + 1) * 4 + g];
    __builtin_amdgcn_sched_barrier(0);     // pin the 19-load batch above
    CONSUMEM(v0, v1, wx, wy3, c, k);
    c = c_nxt;
  }
}

// ---- non-pipelined sorted variant (perm but no xs tier) ----
__global__ __launch_bounds__(256) void sample4s_k(const float* __restrict__ xin,
                                                  const float* __restrict__ T,
                                                  const int* __restrict__ perm,
                                                  float* __restrict__ out) {
  const int lane = threadIdx.x & 63;
  const int g = lane >> 4;
  const int sl = lane & 15;
  const int b = blockIdx.x;
  const int wix = (b >> 3) * 4 + (threadIdx.x >> 6);
  const int q = (b & 7) * 32 + (wix >> 6);
  const int s = wix & 63;
  const int base = s * SUBSZ + q * 32;

  const int j = (lane >= 3) ? (lane - 3) : 0;
  const int fq = j / 6;
  const int rr = j - fq * 6;
  const int isc = rr / 3;
  const int dd = rr - isc * 3;
  const float scale = (float)(1 << fq);
  const float cosoff = isc ? 0.25f : 0.0f;
  const float inv2pi = 0.15915493667125702f;

  const char* Tb = (const char*)T;
  const float4* __restrict__ x4 = (const float4*)xin;
  const int permv = perm[base + (lane & 31)];

  float4 c = x4[__shfl(permv, g, 64)];

  #pragma unroll 2
  for (int k = 0; k < 8; k++) {
    float4 v0[9], v1[9];
    float wx[3], wy3;
    STAGEM(v0, v1, wx, wy3, c);
    float4 c_nxt = c;
    if (k < 7) c_nxt = x4[__shfl(permv, (k + 1) * 4 + g, 64)];
    __builtin_amdgcn_sched_barrier(0);
    CONSUMEM(v0, v1, wx, wy3, c, k);
    c = c_nxt;
  }
}

// ---- unsorted variant (ws fits T only): 2-pt/wave, float2 channel pairs ----
__global__ __launch_bounds__(256) void sample2_k(const float* __restrict__ xin,
                                                 const float* __restrict__ T,
                                                 float* __restrict__ out) {
  const int lane = threadIdx.x & 63;
  const int half = lane >> 5;
  const int l = lane & 31;
  const int wave = blockIdx.x * 4 + (threadIdx.x >> 6);
  const int nW = gridDim.x * 4;
  const int j = (lane >= 3) ? (lane - 3) : 0;
  const int fq = j / 6;
  const int rr = j - fq * 6;
  const int isc = rr / 3;
  const int dd = rr - isc * 3;
  const float scale = (float)(1 << fq);
  const float cosoff = isc ? 0.25f : 0.0f;
  const float inv2pi = 0.15915493667125702f;
  const float4* __restrict__ x4 = (const float4*)xin;

  for (int base = wave * 2; base < P_N; base += nW * 2) {
    const int p = base + half;
    float4 c = x4[p];
    float tn = c.w / 99.0f;
    float gy = 2.0f * tn - 1.0f;
    float iy = ((gy + 1.0f) * 0.5f) * 99.0f;
    float y0f = floorf(iy);
    float wy1 = iy - y0f;
    int row; float wy;
    if (wy1 > 0.5f) { row = (int)y0f + 1; wy = wy1; }
    else            { row = (int)y0f;     wy = 1.0f - wy1; }
    row = min(max(row, 0), NFRAMES - 1);
    const int rowoff = row * TROW;
    float dsum[3];
    float crd[3] = {c.x, c.y, c.z};
    #pragma unroll
    for (int f = 0; f < 3; f++) {
      float prx, pry;
      #pragma unroll
      for (int pl = 0; pl < 3; pl++) {
        float gx = 2.0f * crd[pl] - 1.0f;
        float ix = ((gx + 1.0f) * 0.5f) * 255.0f;
        float x0f = floorf(ix);
        float wx1 = ix - x0f;
        float wx0 = 1.0f - wx1;
        int x0 = (int)x0f;
        const float2* rp = (const float2*)(T + (size_t)(f * 3 + pl) * TPLANE
                                             + (size_t)(rowoff + x0 * CHAN_));
        float2 v0 = rp[l];
        float2 v1 = rp[l + 32];
        float sx = (v0.x * wx0 + v1.x * wx1) * wy;
        float sy = (v0.y * wx0 + v1.y * wx1) * wy;
        if (pl == 0) { prx = sx; pry = sy; }
        else         { prx *= sx; pry *= sy; }
      }
      float r = prx + pry;
      #pragma unroll
      for (int m = 16; m > 0; m >>= 1) r += __shfl_xor(r, m, 64);
      dsum[f] = r;
    }
    float px = c.x + dsum[0];
    float py = c.y + dsum[1];
    float pz = c.z + dsum[2];
    #pragma unroll
    for (int qq = 0; qq < 2; qq++) {
      float qx = __shfl(px, qq * 32, 64);
      float qy = __shfl(py, qq * 32, 64);
      float qz = __shfl(pz, qq * 32, 64);
      float pd = (dd == 0) ? qx : (dd == 1) ? qy : qz;
      float val = hw_sin_rev(pd * scale * inv2pi + cosoff);
      if (lane == 0) val = qx;
      else if (lane == 1) val = qy;
      else if (lane == 2) val = qz;
      if (lane < 63) out[(size_t)(base + qq) * 63 + lane] = val;
    }
  }
}

// ---- fallback (no usable ws): direct-layout sampler ----
__global__ __launch_bounds__(256) void sample_fb_k(const float* __restrict__ xin,
                                                   const float* __restrict__ f0,
                                                   const float* __restrict__ f1,
                                                   const float* __restrict__ f2,
                                                   float* __restrict__ out) {
  const int lane = threadIdx.x & 63;
  int wave = blockIdx.x * 4 + (threadIdx.x >> 6);
  const int nW = gridDim.x * 4;
  for (int p = wave; p < P_N; p += nW) {
    float cx = xin[(size_t)p * 4 + 0];
    float cy = xin[(size_t)p * 4 + 1];
    float cz = xin[(size_t)p * 4 + 2];
    float ct = xin[(size_t)p * 4 + 3];
    float tn = ct / 99.0f;
    float gy = 2.0f * tn - 1.0f;
    float iy = ((gy + 1.0f) * 0.5f) * 99.0f;
    float y0f = floorf(iy);
    float wy1 = iy - y0f;
    float wy0 = 1.0f - wy1;
    int y0 = (int)y0f, y1 = y0 + 1;
    bool y0in = (unsigned)y0 < (unsigned)NFRAMES;
    bool y1in = (unsigned)y1 < (unsigned)NFRAMES;
    int y0c = min(max(y0, 0), NFRAMES - 1);
    int y1c = min(max(y1, 0), NFRAMES - 1);
    float d[3];
    #pragma unroll
    for (int f = 0; f < 3; f++) {
      float prodc;
      #pragma unroll
      for (int pl = 0; pl < 3; pl++) {
        float coord = (pl == 0) ? cx : (pl == 1) ? cy : cz;
        float gx = 2.0f * coord - 1.0f;
        float ix = ((gx + 1.0f) * 0.5f) * 255.0f;
        float x0f = floorf(ix);
        float wx1 = ix - x0f;
        float wx0 = 1.0f - wx1;
        int x0 = (int)x0f, x1 = x0 + 1;
        int x0c = min(max(x0, 0), RESO_ - 1);
        int x1c = min(max(x1, 0), RESO_ - 1);
        const float* ff = (f == 0) ? f0 : (f == 1) ? f1 : f2;
        const float* bse = ff + ((size_t)pl * CHAN_ + lane) * (NFRAMES * RESO_);
        float v00 = y0in ? bse[(size_t)y0c * RESO_ + x0c] : 0.0f;
        float v01 = y0in ? bse[(size_t)y0c * RESO_ + x1c] : 0.0f;
        float v10 = y1in ? bse[(size_t)y1c * RESO_ + x0c] : 0.0f;
        float v11 = y1in ? bse[(size_t)y1c * RESO_ + x1c] : 0.0f;
        float ss2 = v00 * (wy0 * wx0) + v01 * (wy0 * wx1) + v10 * (wy1 * wx0) + v11 * (wy1 * wx1);
        prodc = (pl == 0) ? ss2 : prodc * ss2;
      }
      float sum = prodc;
      #pragma unroll
      for (int o = 32; o > 0; o >>= 1) sum += __shfl_xor(sum, o, 64);
      d[f] = sum;
    }
    float p0 = cx + d[0], p1 = cy + d[1], p2 = cz + d[2];
    if (lane < 63) {
      float val;
      if (lane == 0) val = p0;
      else if (lane == 1) val = p1;
      else if (lane == 2) val = p2;
      else {
        int jj = lane - 3;
        int fq2 = jj / 6;
        int r2 = jj - fq2 * 6;
        int s2 = r2 / 3;
        int d2 = r2 - s2 * 3;
        float pd = (d2 == 0) ? p0 : (d2 == 1) ? p1 : p2;
        float ang = pd * (float)(1 << fq2);
        val = (s2 == 0) ? sinf(ang) : cosf(ang);
      }
      out[(size_t)p * 63 + lane] = val;
    }
  }
}

extern "C" void kernel_launch(void* const* d_in, const int* in_sizes, int n_in,
                              void* d_out, int out_size, void* d_ws, size_t ws_size,
                              hipStream_t stream) {
  const float* x  = (const float*)d_in[0];
  const float* f0 = (const float*)d_in[1];
  const float* f1 = (const float*)d_in[2];
  const float* f2 = (const float*)d_in[3];
  float* out = (float*)d_out;

  const size_t szT    = (size_t)9 * TPLANE * sizeof(float);     // ~59 MB
  const size_t szPerm = (size_t)P_N * sizeof(int);              // 2 MB
  const size_t szXs   = (size_t)P_N * sizeof(float4);           // 8 MB

  if (ws_size >= szT + szPerm + szXs) {
    float* T    = (float*)d_ws;
    int* perm   = (int*)((char*)d_ws + szT);
    float4* xs4 = (float4*)((char*)d_ws + szT + szPerm);
    prep4_k<true><<<dim3(NSUBS + NTRB), dim3(256), 0, stream>>>(f0, f1, f2, T, x, perm, xs4);
    sample4p_k<<<dim3(4096), dim3(256), 0, stream>>>(xs4, T, perm, out);
  } else if (ws_size >= szT + szPerm) {
    float* T  = (float*)d_ws;
    int* perm = (int*)((char*)d_ws + szT);
    prep4_k<false><<<dim3(NSUBS + NTRB), dim3(256), 0, stream>>>(f0, f1, f2, T, x, perm, nullptr);
    sample4s_k<<<dim3(4096), dim3(256), 0, stream>>>(x, T, perm, out);
  } else if (ws_size >= szT) {
    float* T = (float*)d_ws;
    prep4_k<false><<<dim3(NSUBS + NTRB), dim3(256), 0, stream>>>(f0, f1, f2, T, x, nullptr, nullptr);
    sample2_k<<<dim3(4096), dim3(256), 0, stream>>>(x, T, out);
  } else {
    sample_fb_k<<<dim3(8192), dim3(256), 0, stream>>>(x, f0, f1, f2, out);
  }
}

// Round 11
// 137.362 us; speedup vs baseline: 2.0169x; 1.0088x over previous
//
#include <hip/hip_runtime.h>
#include <math.h>

#define P_N 524288
#define NFRAMES 100
#define RESO_ 256
#define CHAN_ 64
#define NFREQ 10

// Transposed layout: T[(f*3+pl)][t][x][c] ; c contiguous
#define TROW   (RESO_ * CHAN_)          // 16384 floats per t-row
#define TPLANE (NFRAMES * TROW)         // 1,638,400 floats per plane

#define NSUBS 64                        // independent sort blocks
#define SUBSZ (P_N / NSUBS)             // 8192 points per sub
#define NKEY (NFRAMES * 128)            // key = t*128 + (x0(cx)>>1)
#define NTRB  (3 * 3 * NFRAMES * 4)     // 3600 transpose blocks

// ---------------- fused prep: 64 per-sub LDS counting-sorts + transpose ----
template <bool WXS>
__global__ __launch_bounds__(256) void prep4_k(const float* __restrict__ f0,
                                               const float* __restrict__ f1,
                                               const float* __restrict__ f2,
                                               float* __restrict__ T,
                                               const float* __restrict__ xin,
                                               int* __restrict__ perm,
                                               float4* __restrict__ xs4) {
  __shared__ unsigned smem[NKEY];
  __shared__ unsigned part[257];

  if (blockIdx.x < NSUBS) {
    if (perm == nullptr) return;
    const int s = blockIdx.x;
    const float4* __restrict__ x4 = (const float4*)xin;
    for (int i = threadIdx.x; i < NKEY; i += 256) smem[i] = 0;
    __syncthreads();
    for (int i = threadIdx.x; i < SUBSZ; i += 256) {
      float4 v = x4[(size_t)s * SUBSZ + i];
      int t = min(max((int)v.w, 0), NFRAMES - 1);
      int x0 = min(max((int)floorf(v.x * 255.0f), 0), 254);
      atomicAdd(&smem[t * 128 + (x0 >> 1)], 1u);
    }
    __syncthreads();
    {
      const int tid = threadIdx.x;
      const int CH = NKEY / 256;         // 50
      unsigned vals[CH];
      unsigned loc = 0;
      #pragma unroll
      for (int i = 0; i < CH; i++) vals[i] = smem[tid * CH + i];
      for (int i = 0; i < CH; i++) { unsigned v = vals[i]; vals[i] = loc; loc += v; }
      part[tid] = loc;
      __syncthreads();
      if (tid == 0) {
        unsigned r = 0;
        for (int jj = 0; jj < 256; jj++) { unsigned v = part[jj]; part[jj] = r; r += v; }
      }
      __syncthreads();
      for (int i = 0; i < CH; i++) smem[tid * CH + i] = part[tid] + vals[i];
      __syncthreads();
    }
    for (int i = threadIdx.x; i < SUBSZ; i += 256) {
      float4 v = x4[(size_t)s * SUBSZ + i];
      int t = min(max((int)v.w, 0), NFRAMES - 1);
      int x0 = min(max((int)floorf(v.x * 255.0f), 0), 254);
      int pos = s * SUBSZ + (int)atomicAdd(&smem[t * 128 + (x0 >> 1)], 1u);
      perm[pos] = s * SUBSZ + i;
      if (WXS) xs4[pos] = v;
    }
    return;
  }

  // ---- transpose blocks ----
  float (*tile)[65] = (float(*)[65])smem;
  int b = blockIdx.x - NSUBS;
  int xblk = b & 3; b >>= 2;
  int t = b % NFRAMES; b /= NFRAMES;
  int pl = b % 3; int f = b / 3;
  const float* src = (f == 0 ? f0 : (f == 1 ? f1 : f2)) + (size_t)pl * CHAN_ * NFRAMES * RESO_;
  int lane = threadIdx.x & 63;
  int w = threadIdx.x >> 6;
  #pragma unroll
  for (int c = 0; c < 16; c++) {
    int cc = w * 16 + c;
    tile[cc][lane] = src[(size_t)cc * (NFRAMES * RESO_) + (size_t)t * RESO_ + xblk * 64 + lane];
  }
  __syncthreads();
  float* dst = T + ((size_t)(f * 3 + pl) * NFRAMES + t) * TROW + (size_t)(xblk * 64) * CHAN_;
  #pragma unroll
  for (int i = 0; i < 16; i++) {
    int xx = w * 16 + i;
    dst[(size_t)xx * CHAN_ + lane] = tile[lane][xx];
  }
}

__device__ __forceinline__ float hw_sin_rev(float rev) {
  float r, s;
  asm("v_fract_f32 %0, %1" : "=v"(r) : "v"(rev));
  asm("v_sin_f32 %0, %1" : "=v"(s) : "v"(r));
  return s;
}

// ---- weights + 3 column byte-offsets for one point-group ----
#define WCOMP(C, WX, WY3, CB)                                                \
  {                                                                          \
    float tn = (C).w * (1.0f / 99.0f);                                       \
    float gy = 2.0f * tn - 1.0f;                                             \
    float iy = ((gy + 1.0f) * 0.5f) * 99.0f;                                 \
    float y0f = floorf(iy);                                                  \
    float wy1 = iy - y0f;                                                    \
    int row; float wy;                                                       \
    if (wy1 > 0.5f) { row = (int)y0f + 1; wy = wy1; }                        \
    else            { row = (int)y0f;     wy = 1.0f - wy1; }                 \
    row = min(max(row, 0), NFRAMES - 1);                                     \
    (WY3) = wy * wy * wy;                                                    \
    const unsigned rowbyte = ((unsigned)row << 16) + ((unsigned)sl << 4);    \
    { float gx = 2.0f * (C).x - 1.0f; float ix = ((gx + 1.0f) * 0.5f) * 255.0f; \
      float x0f = floorf(ix); (WX)[0] = ix - x0f;                            \
      (CB)[0] = rowbyte + ((unsigned)(int)x0f << 8); }                       \
    { float gx = 2.0f * (C).y - 1.0f; float ix = ((gx + 1.0f) * 0.5f) * 255.0f; \
      float x0f = floorf(ix); (WX)[1] = ix - x0f;                            \
      (CB)[1] = rowbyte + ((unsigned)(int)x0f << 8); }                       \
    { float gx = 2.0f * (C).z - 1.0f; float ix = ((gx + 1.0f) * 0.5f) * 255.0f; \
      float x0f = floorf(ix); (WX)[2] = ix - x0f;                            \
      (CB)[2] = rowbyte + ((unsigned)(int)x0f << 8); }                       \
  }

// ---- issue one feat's 6 row loads (3 planes x {x0, x0+1}) ----
#define FSTAGE(V0, V1, F, CB)                                                \
  {                                                                          \
    _Pragma("unroll")                                                        \
    for (int pl = 0; pl < 3; pl++) {                                         \
      const char* bp = Tb + (size_t)((F) * 3 + pl) * ((size_t)TPLANE * 4);   \
      unsigned cb = (CB)[pl];                                                \
      (V0)[pl] = *(const float4*)(bp + cb);                                  \
      (V1)[pl] = *(const float4*)(bp + cb + 256);                            \
    }                                                                        \
  }

// ---- consume one feat: lerp x3, product, 16-group reduce -> DST ----
#define FCONS(V0, V1, WX, WY3, DST)                                          \
  {                                                                          \
    float prx, pry, prz, prw;                                                \
    _Pragma("unroll")                                                        \
    for (int pl = 0; pl < 3; pl++) {                                         \
      float w1 = (WX)[pl];                                                   \
      float sx = fmaf(w1, (V1)[pl].x - (V0)[pl].x, (V0)[pl].x);              \
      float sy = fmaf(w1, (V1)[pl].y - (V0)[pl].y, (V0)[pl].y);              \
      float sz = fmaf(w1, (V1)[pl].z - (V0)[pl].z, (V0)[pl].z);              \
      float sw = fmaf(w1, (V1)[pl].w - (V0)[pl].w, (V0)[pl].w);              \
      if (pl == 0) { prx = sx; pry = sy; prz = sz; prw = sw; }               \
      else         { prx *= sx; pry *= sy; prz *= sz; prw *= sw; }           \
    }                                                                        \
    float r = ((prx + pry) + (prz + prw)) * (WY3);                           \
    _Pragma("unroll")                                                        \
    for (int m = 8; m > 0; m >>= 1) r += __shfl_xor(r, m, 64);               \
    (DST) = r;                                                               \
  }

// ---- PE + 4 coalesced stores for one point-group ----
#define PESTORE(D0, D1, D2, C, KIDX)                                         \
  {                                                                          \
    float px = (C).x + (D0);                                                 \
    float py = (C).y + (D1);                                                 \
    float pz = (C).z + (D2);                                                 \
    _Pragma("unroll")                                                        \
    for (int q2 = 0; q2 < 4; q2++) {                                         \
      float qx = __shfl(px, q2 * 16, 64);                                    \
      float qy = __shfl(py, q2 * 16, 64);                                    \
      float qz = __shfl(pz, q2 * 16, 64);                                    \
      int pq = __shfl(permv, (KIDX) * 4 + q2, 64);                           \
      float pd = (dd == 0) ? qx : (dd == 1) ? qy : qz;                       \
      float val = hw_sin_rev(pd * scale * inv2pi + cosoff);                  \
      if (lane == 0) val = qx;                                               \
      else if (lane == 1) val = qy;                                          \
      else if (lane == 2) val = qz;                                          \
      if (lane < 63)                                                         \
        __builtin_nontemporal_store(val, &out[(size_t)pq * 63 + lane]);      \
    }                                                                        \
  }

// 4 points/iter; feat-level depth-1 pipeline, 2 named sets (A/B), every
// stage pinned with sched_barrier(0) -> counted vmcnt, never a drain.
// Peak live load-regs = 12 float4 (48 VGPR) -> fits 4 waves/SIMD.
__global__ __launch_bounds__(256, 4) void sample4q_k(const float4* __restrict__ xs4,
                                                     const float* __restrict__ T,
                                                     const int* __restrict__ perm,
                                                     float* __restrict__ out) {
  const int lane = threadIdx.x & 63;
  const int g = lane >> 4;
  const int sl = lane & 15;
  const int b = blockIdx.x;         // 4096 blocks
  const int wix = (b >> 3) * 4 + (threadIdx.x >> 6);   // 0..2047 within XCD
  const int q = (b & 7) * 32 + (wix >> 6);             // chunk 0..255 (~t)
  const int s = wix & 63;                              // sub 0..63
  const int base = s * SUBSZ + q * 32;                 // 32 points per wave

  const int j = (lane >= 3) ? (lane - 3) : 0;
  const int fq = j / 6;
  const int rr = j - fq * 6;
  const int isc = rr / 3;
  const int dd = rr - isc * 3;
  const float scale = (float)(1 << fq);
  const float cosoff = isc ? 0.25f : 0.0f;
  const float inv2pi = 0.15915493667125702f;

  const char* Tb = (const char*)T;
  const int permv = perm[base + (lane & 31)];

  float4 vA0[3], vA1[3], vB0[3], vB1[3];
  float wxC[3], wy3C; unsigned cbC[3];
  float wxN[3], wy3N; unsigned cbN[3];
  float4 cC, cN;
  float d0, d1, d2;

  cC = xs4[base + g];
  WCOMP(cC, wxC, wy3C, cbC);
  FSTAGE(vA0, vA1, 0, cbC);
  __builtin_amdgcn_sched_barrier(0);

  #pragma unroll 1
  for (int kk = 0; kk < 4; kk++) {
    const int k = kk * 2;
    // ---- group k (even): current in C, f0 staged in A ----
    FSTAGE(vB0, vB1, 1, cbC);
    __builtin_amdgcn_sched_barrier(0);
    FCONS(vA0, vA1, wxC, wy3C, d0);          // waits counted vmcnt (B in flight)
    FSTAGE(vA0, vA1, 2, cbC);
    __builtin_amdgcn_sched_barrier(0);
    FCONS(vB0, vB1, wxC, wy3C, d1);
    cN = xs4[base + (k + 1) * 4 + g];        // next group's coords
    WCOMP(cN, wxN, wy3N, cbN);
    FSTAGE(vB0, vB1, 0, cbN);                // next group's f0
    __builtin_amdgcn_sched_barrier(0);
    FCONS(vA0, vA1, wxC, wy3C, d2);
    PESTORE(d0, d1, d2, cC, k);
    // ---- group k+1 (odd): current in N, f0 staged in B ----
    FSTAGE(vA0, vA1, 1, cbN);
    __builtin_amdgcn_sched_barrier(0);
    FCONS(vB0, vB1, wxN, wy3N, d0);
    FSTAGE(vB0, vB1, 2, cbN);
    __builtin_amdgcn_sched_barrier(0);
    FCONS(vA0, vA1, wxN, wy3N, d1);
    {
      int nidx = min(base + (k + 2) * 4 + g, P_N - 1);   // clamp for last wave
      cC = xs4[nidx];
    }
    WCOMP(cC, wxC, wy3C, cbC);
    FSTAGE(vA0, vA1, 0, cbC);                // group k+2's f0 (last iter: dummy)
    __builtin_amdgcn_sched_barrier(0);
    FCONS(vB0, vB1, wxN, wy3N, d2);
    PESTORE(d0, d1, d2, cN, k + 1);
  }
}

// ---- legacy monolithic-batch macros for fallback tiers ----
#define STAGEM(V0, V1, WX, WY3, C)                                           \
  {                                                                          \
    float wy3t; unsigned cbt[3];                                             \
    WCOMP(C, WX, wy3t, cbt);                                                 \
    (WY3) = wy3t;                                                            \
    _Pragma("unroll")                                                        \
    for (int ss = 0; ss < 9; ss++) {                                         \
      const char* bp = Tb + (size_t)ss * ((size_t)TPLANE * 4);               \
      unsigned cb = cbt[ss % 3];                                             \
      (V0)[ss] = *(const float4*)(bp + cb);                                  \
      (V1)[ss] = *(const float4*)(bp + cb + 256);                            \
    }                                                                        \
  }

#define CONSUMEM(V0, V1, WX, WY3, C, KIDX)                                   \
  {                                                                          \
    float dsum[3];                                                           \
    _Pragma("unroll")                                                        \
    for (int f = 0; f < 3; f++) {                                            \
      float prx, pry, prz, prw;                                              \
      _Pragma("unroll")                                                      \
      for (int pl = 0; pl < 3; pl++) {                                       \
        int ss = f * 3 + pl;                                                 \
        float w1 = (WX)[pl];                                                 \
        float sx = fmaf(w1, (V1)[ss].x - (V0)[ss].x, (V0)[ss].x);            \
        float sy = fmaf(w1, (V1)[ss].y - (V0)[ss].y, (V0)[ss].y);            \
        float sz = fmaf(w1, (V1)[ss].z - (V0)[ss].z, (V0)[ss].z);            \
        float sw = fmaf(w1, (V1)[ss].w - (V0)[ss].w, (V0)[ss].w);            \
        if (pl == 0) { prx = sx; pry = sy; prz = sz; prw = sw; }             \
        else         { prx *= sx; pry *= sy; prz *= sz; prw *= sw; }         \
      }                                                                      \
      float r = ((prx + pry) + (prz + prw)) * (WY3);                         \
      _Pragma("unroll")                                                      \
      for (int m = 8; m > 0; m >>= 1) r += __shfl_xor(r, m, 64);             \
      dsum[f] = r;                                                           \
    }                                                                        \
    PESTORE(dsum[0], dsum[1], dsum[2], C, KIDX);                             \
  }

// ---- non-xs tier ----
__global__ __launch_bounds__(256) void sample4s_k(const float* __restrict__ xin,
                                                  const float* __restrict__ T,
                                                  const int* __restrict__ perm,
                                                  float* __restrict__ out) {
  const int lane = threadIdx.x & 63;
  const int g = lane >> 4;
  const int sl = lane & 15;
  const int b = blockIdx.x;
  const int wix = (b >> 3) * 4 + (threadIdx.x >> 6);
  const int q = (b & 7) * 32 + (wix >> 6);
  const int s = wix & 63;
  const int base = s * SUBSZ + q * 32;

  const int j = (lane >= 3) ? (lane - 3) : 0;
  const int fq = j / 6;
  const int rr = j - fq * 6;
  const int isc = rr / 3;
  const int dd = rr - isc * 3;
  const float scale = (float)(1 << fq);
  const float cosoff = isc ? 0.25f : 0.0f;
  const float inv2pi = 0.15915493667125702f;

  const char* Tb = (const char*)T;
  const float4* __restrict__ x4 = (const float4*)xin;
  const int permv = perm[base + (lane & 31)];

  float4 c = x4[__shfl(permv, g, 64)];

  #pragma unroll 2
  for (int k = 0; k < 8; k++) {
    float4 v0[9], v1[9];
    float wx[3], wy3;
    STAGEM(v0, v1, wx, wy3, c);
    float4 c_nxt = c;
    if (k < 7) c_nxt = x4[__shfl(permv, (k + 1) * 4 + g, 64)];
    __builtin_amdgcn_sched_barrier(0);
    CONSUMEM(v0, v1, wx, wy3, c, k);
    c = c_nxt;
  }
}

// ---- unsorted variant (ws fits T only) ----
__global__ __launch_bounds__(256) void sample2_k(const float* __restrict__ xin,
                                                 const float* __restrict__ T,
                                                 float* __restrict__ out) {
  const int lane = threadIdx.x & 63;
  const int half = lane >> 5;
  const int l = lane & 31;
  const int wave = blockIdx.x * 4 + (threadIdx.x >> 6);
  const int nW = gridDim.x * 4;
  const int j = (lane >= 3) ? (lane - 3) : 0;
  const int fq = j / 6;
  const int rr = j - fq * 6;
  const int isc = rr / 3;
  const int dd = rr - isc * 3;
  const float scale = (float)(1 << fq);
  const float cosoff = isc ? 0.25f : 0.0f;
  const float inv2pi = 0.15915493667125702f;
  const float4* __restrict__ x4 = (const float4*)xin;

  for (int base = wave * 2; base < P_N; base += nW * 2) {
    const int p = base + half;
    float4 c = x4[p];
    float tn = c.w / 99.0f;
    float gy = 2.0f * tn - 1.0f;
    float iy = ((gy + 1.0f) * 0.5f) * 99.0f;
    float y0f = floorf(iy);
    float wy1 = iy - y0f;
    int row; float wy;
    if (wy1 > 0.5f) { row = (int)y0f + 1; wy = wy1; }
    else            { row = (int)y0f;     wy = 1.0f - wy1; }
    row = min(max(row, 0), NFRAMES - 1);
    const int rowoff = row * TROW;
    float dsum[3];
    float crd[3] = {c.x, c.y, c.z};
    #pragma unroll
    for (int f = 0; f < 3; f++) {
      float prx, pry;
      #pragma unroll
      for (int pl = 0; pl < 3; pl++) {
        float gx = 2.0f * crd[pl] - 1.0f;
        float ix = ((gx + 1.0f) * 0.5f) * 255.0f;
        float x0f = floorf(ix);
        float wx1 = ix - x0f;
        float wx0 = 1.0f - wx1;
        int x0 = (int)x0f;
        const float2* rp = (const float2*)(T + (size_t)(f * 3 + pl) * TPLANE
                                             + (size_t)(rowoff + x0 * CHAN_));
        float2 v0 = rp[l];
        float2 v1 = rp[l + 32];
        float sx = (v0.x * wx0 + v1.x * wx1) * wy;
        float sy = (v0.y * wx0 + v1.y * wx1) * wy;
        if (pl == 0) { prx = sx; pry = sy; }
        else         { prx *= sx; pry *= sy; }
      }
      float r = prx + pry;
      #pragma unroll
      for (int m = 16; m > 0; m >>= 1) r += __shfl_xor(r, m, 64);
      dsum[f] = r;
    }
    float px = c.x + dsum[0];
    float py = c.y + dsum[1];
    float pz = c.z + dsum[2];
    #pragma unroll
    for (int qq = 0; qq < 2; qq++) {
      float qx = __shfl(px, qq * 32, 64);
      float qy = __shfl(py, qq * 32, 64);
      float qz = __shfl(pz, qq * 32, 64);
      float pd = (dd == 0) ? qx : (dd == 1) ? qy : qz;
      float val = hw_sin_rev(pd * scale * inv2pi + cosoff);
      if (lane == 0) val = qx;
      else if (lane == 1) val = qy;
      else if (lane == 2) val = qz;
      if (lane < 63) out[(size_t)(base + qq) * 63 + lane] = val;
    }
  }
}

// ---- fallback (no usable ws) ----
__global__ __launch_bounds__(256) void sample_fb_k(const float* __restrict__ xin,
                                                   const float* __restrict__ f0,
                                                   const float* __restrict__ f1,
                                                   const float* __restrict__ f2,
                                                   float* __restrict__ out) {
  const int lane = threadIdx.x & 63;
  int wave = blockIdx.x * 4 + (threadIdx.x >> 6);
  const int nW = gridDim.x * 4;
  for (int p = wave; p < P_N; p += nW) {
    float cx = xin[(size_t)p * 4 + 0];
    float cy = xin[(size_t)p * 4 + 1];
    float cz = xin[(size_t)p * 4 + 2];
    float ct = xin[(size_t)p * 4 + 3];
    float tn = ct / 99.0f;
    float gy = 2.0f * tn - 1.0f;
    float iy = ((gy + 1.0f) * 0.5f) * 99.0f;
    float y0f = floorf(iy);
    float wy1 = iy - y0f;
    float wy0 = 1.0f - wy1;
    int y0 = (int)y0f, y1 = y0 + 1;
    bool y0in = (unsigned)y0 < (unsigned)NFRAMES;
    bool y1in = (unsigned)y1 < (unsigned)NFRAMES;
    int y0c = min(max(y0, 0), NFRAMES - 1);
    int y1c = min(max(y1, 0), NFRAMES - 1);
    float d[3];
    #pragma unroll
    for (int f = 0; f < 3; f++) {
      float prodc;
      #pragma unroll
      for (int pl = 0; pl < 3; pl++) {
        float coord = (pl == 0) ? cx : (pl == 1) ? cy : cz;
        float gx = 2.0f * coord - 1.0f;
        float ix = ((gx + 1.0f) * 0.5f) * 255.0f;
        float x0f = floorf(ix);
        float wx1 = ix - x0f;
        float wx0 = 1.0f - wx1;
        int x0 = (int)x0f, x1 = x0 + 1;
        int x0c = min(max(x0, 0), RESO_ - 1);
        int x1c = min(max(x1, 0), RESO_ - 1);
        const float* ff = (f == 0) ? f0 : (f == 1) ? f1 : f2;
        const float* bse = ff + ((size_t)pl * CHAN_ + lane) * (NFRAMES * RESO_);
        float v00 = y0in ? bse[(size_t)y0c * RESO_ + x0c] : 0.0f;
        float v01 = y0in ? bse[(size_t)y0c * RESO_ + x1c] : 0.0f;
        float v10 = y1in ? bse[(size_t)y1c * RESO_ + x0c] : 0.0f;
        float v11 = y1in ? bse[(size_t)y1c * RESO_ + x1c] : 0.0f;
        float ss2 = v00 * (wy0 * wx0) + v01 * (wy0 * wx1) + v10 * (wy1 * wx0) + v11 * (wy1 * wx1);
        prodc = (pl == 0) ? ss2 : prodc * ss2;
      }
      float sum = prodc;
      #pragma unroll
      for (int o = 32; o > 0; o >>= 1) sum += __shfl_xor(sum, o, 64);
      d[f] = sum;
    }
    float p0 = cx + d[0], p1 = cy + d[1], p2 = cz + d[2];
    if (lane < 63) {
      float val;
      if (lane == 0) val = p0;
      else if (lane == 1) val = p1;
      else if (lane == 2) val = p2;
      else {
        int jj = lane - 3;
        int fq2 = jj / 6;
        int r2 = jj - fq2 * 6;
        int s2 = r2 / 3;
        int d2 = r2 - s2 * 3;
        float pd = (d2 == 0) ? p0 : (d2 == 1) ? p1 : p2;
        float ang = pd * (float)(1 << fq2);
        val = (s2 == 0) ? sinf(ang) : cosf(ang);
      }
      out[(size_t)p * 63 + lane] = val;
    }
  }
}

extern "C" void kernel_launch(void* const* d_in, const int* in_sizes, int n_in,
                              void* d_out, int out_size, void* d_ws, size_t ws_size,
                              hipStream_t stream) {
  const float* x  = (const float*)d_in[0];
  const float* f0 = (const float*)d_in[1];
  const float* f1 = (const float*)d_in[2];
  const float* f2 = (const float*)d_in[3];
  float* out = (float*)d_out;

  const size_t szT    = (size_t)9 * TPLANE * sizeof(float);     // ~59 MB
  const size_t szPerm = (size_t)P_N * sizeof(int);              // 2 MB
  const size_t szXs   = (size_t)P_N * sizeof(float4);           // 8 MB

  if (ws_size >= szT + szPerm + szXs) {
    float* T    = (float*)d_ws;
    int* perm   = (int*)((char*)d_ws + szT);
    float4* xs4 = (float4*)((char*)d_ws + szT + szPerm);
    prep4_k<true><<<dim3(NSUBS + NTRB), dim3(256), 0, stream>>>(f0, f1, f2, T, x, perm, xs4);
    sample4q_k<<<dim3(4096), dim3(256), 0, stream>>>(xs4, T, perm, out);
  } else if (ws_size >= szT + szPerm) {
    float* T  = (float*)d_ws;
    int* perm = (int*)((char*)d_ws + szT);
    prep4_k<false><<<dim3(NSUBS + NTRB), dim3(256), 0, stream>>>(f0, f1, f2, T, x, perm, nullptr);
    sample4s_k<<<dim3(4096), dim3(256), 0, stream>>>(x, T, perm, out);
  } else if (ws_size >= szT) {
    float* T = (float*)d_ws;
    prep4_k<false><<<dim3(NSUBS + NTRB), dim3(256), 0, stream>>>(f0, f1, f2, T, x, nullptr, nullptr);
    sample2_k<<<dim3(4096), dim3(256), 0, stream>>>(x, T, out);
  } else {
    sample_fb_k<<<dim3(8192), dim3(256), 0, stream>>>(x, f0, f1, f2, out);
  }
}

// Round 12
// 121.923 us; speedup vs baseline: 2.2723x; 1.1266x over previous
//
#include <hip/hip_runtime.h>
#include <math.h>

#define P_N 524288
#define NFRAMES 100
#define RESO_ 256
#define CHAN_ 64
#define NFREQ 10

// f32 transposed layout (fallback tiers): T[(f*3+pl)][t][x][c]
#define TROW   (RESO_ * CHAN_)          // 16384 floats per t-row
#define TPLANE (NFRAMES * TROW)         // 1,638,400 floats per plane

// fp16 transposed layout (main tier): row = 64 ch * 2B = 128 B = 1 line
#define T2PLANE_B ((size_t)NFRAMES * RESO_ * CHAN_ * 2)   // 3,276,800 B

#define NSUBS 64                        // independent sort blocks
#define SUBSZ (P_N / NSUBS)             // 8192 points per sub
#define NKEY (NFRAMES * 128)            // key = t*128 + (x0(cx)>>1)
#define NTRB  (3 * 3 * NFRAMES * 4)     // 3600 transpose blocks

// ---------------- fused prep: 64 per-sub LDS counting-sorts + transpose ----
template <typename TO, bool WXS>
__global__ __launch_bounds__(256) void prep5_k(const float* __restrict__ f0,
                                               const float* __restrict__ f1,
                                               const float* __restrict__ f2,
                                               TO* __restrict__ T,
                                               const float* __restrict__ xin,
                                               int* __restrict__ perm,
                                               float4* __restrict__ xs4) {
  __shared__ unsigned smem[NKEY];
  __shared__ unsigned part[257];

  if (blockIdx.x < NSUBS) {
    if (perm == nullptr) return;
    const int s = blockIdx.x;
    const float4* __restrict__ x4 = (const float4*)xin;
    for (int i = threadIdx.x; i < NKEY; i += 256) smem[i] = 0;
    __syncthreads();
    for (int i = threadIdx.x; i < SUBSZ; i += 256) {
      float4 v = x4[(size_t)s * SUBSZ + i];
      int t = min(max((int)v.w, 0), NFRAMES - 1);
      int x0 = min(max((int)floorf(v.x * 255.0f), 0), 254);
      atomicAdd(&smem[t * 128 + (x0 >> 1)], 1u);
    }
    __syncthreads();
    {
      const int tid = threadIdx.x;
      const int CH = NKEY / 256;         // 50
      unsigned vals[CH];
      unsigned loc = 0;
      #pragma unroll
      for (int i = 0; i < CH; i++) vals[i] = smem[tid * CH + i];
      for (int i = 0; i < CH; i++) { unsigned v = vals[i]; vals[i] = loc; loc += v; }
      part[tid] = loc;
      __syncthreads();
      if (tid == 0) {
        unsigned r = 0;
        for (int jj = 0; jj < 256; jj++) { unsigned v = part[jj]; part[jj] = r; r += v; }
      }
      __syncthreads();
      for (int i = 0; i < CH; i++) smem[tid * CH + i] = part[tid] + vals[i];
      __syncthreads();
    }
    for (int i = threadIdx.x; i < SUBSZ; i += 256) {
      float4 v = x4[(size_t)s * SUBSZ + i];
      int t = min(max((int)v.w, 0), NFRAMES - 1);
      int x0 = min(max((int)floorf(v.x * 255.0f), 0), 254);
      int pos = s * SUBSZ + (int)atomicAdd(&smem[t * 128 + (x0 >> 1)], 1u);
      perm[pos] = s * SUBSZ + i;
      if (WXS) xs4[pos] = v;
    }
    return;
  }

  // ---- transpose blocks (write TO: float or _Float16 RTN) ----
  float (*tile)[65] = (float(*)[65])smem;
  int b = blockIdx.x - NSUBS;
  int xblk = b & 3; b >>= 2;
  int t = b % NFRAMES; b /= NFRAMES;
  int pl = b % 3; int f = b / 3;
  const float* src = (f == 0 ? f0 : (f == 1 ? f1 : f2)) + (size_t)pl * CHAN_ * NFRAMES * RESO_;
  int lane = threadIdx.x & 63;
  int w = threadIdx.x >> 6;
  #pragma unroll
  for (int c = 0; c < 16; c++) {
    int cc = w * 16 + c;
    tile[cc][lane] = src[(size_t)cc * (NFRAMES * RESO_) + (size_t)t * RESO_ + xblk * 64 + lane];
  }
  __syncthreads();
  TO* dst = T + (((size_t)(f * 3 + pl) * NFRAMES + t) * RESO_ + (size_t)(xblk * 64)) * CHAN_;
  #pragma unroll
  for (int i = 0; i < 16; i++) {
    int xx = w * 16 + i;
    dst[(size_t)xx * CHAN_ + lane] = (TO)tile[lane][xx];
  }
}

__device__ __forceinline__ float hw_sin_rev(float rev) {
  float r, s;
  asm("v_fract_f32 %0, %1" : "=v"(r) : "v"(rev));
  asm("v_sin_f32 %0, %1" : "=v"(s) : "v"(r));
  return s;
}

union U16x8 { uint4 u; _Float16 h[8]; };

// 8 points per wave iteration: lane-group g = lane>>3 owns point k*8+g.
// Each 8-lane group loads a full 64-ch fp16 row as uint4 (128 B = 1 line).
// 18 row loads + coord prefetch batched, sched_barrier(0) pins the batch.
__global__ __launch_bounds__(256) void sample8h_k(const float4* __restrict__ xs4,
                                                  const _Float16* __restrict__ T,
                                                  const int* __restrict__ perm,
                                                  float* __restrict__ out) {
  const int lane = threadIdx.x & 63;
  const int g = lane >> 3;          // group 0..7
  const int sl = lane & 7;          // sub-lane in group
  const int b = blockIdx.x;         // 4096 blocks
  const int wix = (b >> 3) * 4 + (threadIdx.x >> 6);   // 0..2047 within XCD
  const int q = (b & 7) * 32 + (wix >> 6);             // chunk 0..255 (~t)
  const int s = wix & 63;                              // sub 0..63
  const int base = s * SUBSZ + q * 32;                 // 32 points per wave

  // per-lane PE constants (output element id = lane, valid for lane<63)
  const int j = (lane >= 3) ? (lane - 3) : 0;
  const int fq = j / 6;
  const int rr = j - fq * 6;
  const int isc = rr / 3;
  const int dd = rr - isc * 3;
  const float scale = (float)(1 << fq);
  const float cosoff = isc ? 0.25f : 0.0f;
  const float inv2pi = 0.15915493667125702f;

  const char* Tb = (const char*)T;
  const int permv = perm[base + (lane & 31)];

  float4 c = xs4[base + g];

  #pragma unroll
  for (int k = 0; k < 4; k++) {
    // ---- weights + 3 column byte-offsets (fp16 layout) ----
    float tn = c.w * (1.0f / 99.0f);
    float gy = 2.0f * tn - 1.0f;
    float iy = ((gy + 1.0f) * 0.5f) * 99.0f;
    float y0f = floorf(iy);
    float wy1 = iy - y0f;
    int row; float wy;
    if (wy1 > 0.5f) { row = (int)y0f + 1; wy = wy1; }
    else            { row = (int)y0f;     wy = 1.0f - wy1; }
    row = min(max(row, 0), NFRAMES - 1);
    float wy3 = wy * wy * wy;
    const unsigned rowbyte = ((unsigned)row << 15) + ((unsigned)sl << 4);
    float wx[3]; unsigned cb[3];
    { float gx = 2.0f * c.x - 1.0f; float ix = ((gx + 1.0f) * 0.5f) * 255.0f;
      float x0f = floorf(ix); wx[0] = ix - x0f;
      cb[0] = rowbyte + ((unsigned)(int)x0f << 7); }
    { float gx = 2.0f * c.y - 1.0f; float ix = ((gx + 1.0f) * 0.5f) * 255.0f;
      float x0f = floorf(ix); wx[1] = ix - x0f;
      cb[1] = rowbyte + ((unsigned)(int)x0f << 7); }
    { float gx = 2.0f * c.z - 1.0f; float ix = ((gx + 1.0f) * 0.5f) * 255.0f;
      float x0f = floorf(ix); wx[2] = ix - x0f;
      cb[2] = rowbyte + ((unsigned)(int)x0f << 7); }

    // ---- 18 row loads (x0 and x0+1 rows per plane) ----
    U16x8 v0[9], v1[9];
    #pragma unroll
    for (int ss = 0; ss < 9; ss++) {
      const char* bp = Tb + (size_t)ss * T2PLANE_B;
      unsigned cbs = cb[ss % 3];
      v0[ss].u = *(const uint4*)(bp + cbs);
      v1[ss].u = *(const uint4*)(bp + cbs + 128);
    }
    float4 c_nxt = c;
    if (k < 3) c_nxt = xs4[base + (k + 1) * 8 + g];
    __builtin_amdgcn_sched_barrier(0);     // pin the load batch above

    // ---- consume: cvt->f32, lerp, per-channel product, 8-lane reduce ----
    float dsum[3];
    #pragma unroll
    for (int f = 0; f < 3; f++) {
      float pr[8];
      #pragma unroll
      for (int pl = 0; pl < 3; pl++) {
        int ss = f * 3 + pl;
        float w1 = wx[pl];
        #pragma unroll
        for (int ch = 0; ch < 8; ch++) {
          float av = (float)v0[ss].h[ch];
          float bv = (float)v1[ss].h[ch];
          float sv = fmaf(w1, bv - av, av);
          pr[ch] = (pl == 0) ? sv : pr[ch] * sv;
        }
      }
      float r = (((pr[0] + pr[1]) + (pr[2] + pr[3])) +
                 ((pr[4] + pr[5]) + (pr[6] + pr[7]))) * wy3;
      #pragma unroll
      for (int m = 4; m > 0; m >>= 1) r += __shfl_xor(r, m, 64);  // 8-group
      dsum[f] = r;
    }

    float px = c.x + dsum[0];
    float py = c.y + dsum[1];
    float pz = c.z + dsum[2];

    // ---- PE + store: 8 rounds, one point each ----
    #pragma unroll
    for (int q2 = 0; q2 < 8; q2++) {
      float qx = __shfl(px, q2 * 8, 64);
      float qy = __shfl(py, q2 * 8, 64);
      float qz = __shfl(pz, q2 * 8, 64);
      int pq = __shfl(permv, k * 8 + q2, 64);
      float pd = (dd == 0) ? qx : (dd == 1) ? qy : qz;
      float val = hw_sin_rev(pd * scale * inv2pi + cosoff);
      if (lane == 0) val = qx;
      else if (lane == 1) val = qy;
      else if (lane == 2) val = qz;
      if (lane < 63)
        __builtin_nontemporal_store(val, &out[(size_t)pq * 63 + lane]);
    }

    c = c_nxt;
  }
}

// ---- fallback (ws fits f32 T only): 2-pt/wave, float2 channel pairs ----
__global__ __launch_bounds__(256) void sample2_k(const float* __restrict__ xin,
                                                 const float* __restrict__ T,
                                                 float* __restrict__ out) {
  const int lane = threadIdx.x & 63;
  const int half = lane >> 5;
  const int l = lane & 31;
  const int wave = blockIdx.x * 4 + (threadIdx.x >> 6);
  const int nW = gridDim.x * 4;
  const int j = (lane >= 3) ? (lane - 3) : 0;
  const int fq = j / 6;
  const int rr = j - fq * 6;
  const int isc = rr / 3;
  const int dd = rr - isc * 3;
  const float scale = (float)(1 << fq);
  const float cosoff = isc ? 0.25f : 0.0f;
  const float inv2pi = 0.15915493667125702f;
  const float4* __restrict__ x4 = (const float4*)xin;

  for (int base = wave * 2; base < P_N; base += nW * 2) {
    const int p = base + half;
    float4 c = x4[p];
    float tn = c.w / 99.0f;
    float gy = 2.0f * tn - 1.0f;
    float iy = ((gy + 1.0f) * 0.5f) * 99.0f;
    float y0f = floorf(iy);
    float wy1 = iy - y0f;
    int row; float wy;
    if (wy1 > 0.5f) { row = (int)y0f + 1; wy = wy1; }
    else            { row = (int)y0f;     wy = 1.0f - wy1; }
    row = min(max(row, 0), NFRAMES - 1);
    const int rowoff = row * TROW;
    float dsum[3];
    float crd[3] = {c.x, c.y, c.z};
    #pragma unroll
    for (int f = 0; f < 3; f++) {
      float prx, pry;
      #pragma unroll
      for (int pl = 0; pl < 3; pl++) {
        float gx = 2.0f * crd[pl] - 1.0f;
        float ix = ((gx + 1.0f) * 0.5f) * 255.0f;
        float x0f = floorf(ix);
        float wx1 = ix - x0f;
        float wx0 = 1.0f - wx1;
        int x0 = (int)x0f;
        const float2* rp = (const float2*)(T + (size_t)(f * 3 + pl) * TPLANE
                                             + (size_t)(rowoff + x0 * CHAN_));
        float2 v0 = rp[l];
        float2 v1 = rp[l + 32];
        float sx = (v0.x * wx0 + v1.x * wx1) * wy;
        float sy = (v0.y * wx0 + v1.y * wx1) * wy;
        if (pl == 0) { prx = sx; pry = sy; }
        else         { prx *= sx; pry *= sy; }
      }
      float r = prx + pry;
      #pragma unroll
      for (int m = 16; m > 0; m >>= 1) r += __shfl_xor(r, m, 64);
      dsum[f] = r;
    }
    float px = c.x + dsum[0];
    float py = c.y + dsum[1];
    float pz = c.z + dsum[2];
    #pragma unroll
    for (int qq = 0; qq < 2; qq++) {
      float qx = __shfl(px, qq * 32, 64);
      float qy = __shfl(py, qq * 32, 64);
      float qz = __shfl(pz, qq * 32, 64);
      float pd = (dd == 0) ? qx : (dd == 1) ? qy : qz;
      float val = hw_sin_rev(pd * scale * inv2pi + cosoff);
      if (lane == 0) val = qx;
      else if (lane == 1) val = qy;
      else if (lane == 2) val = qz;
      if (lane < 63) out[(size_t)(base + qq) * 63 + lane] = val;
    }
  }
}

// ---- fallback (no usable ws): direct-layout sampler ----
__global__ __launch_bounds__(256) void sample_fb_k(const float* __restrict__ xin,
                                                   const float* __restrict__ f0,
                                                   const float* __restrict__ f1,
                                                   const float* __restrict__ f2,
                                                   float* __restrict__ out) {
  const int lane = threadIdx.x & 63;
  int wave = blockIdx.x * 4 + (threadIdx.x >> 6);
  const int nW = gridDim.x * 4;
  for (int p = wave; p < P_N; p += nW) {
    float cx = xin[(size_t)p * 4 + 0];
    float cy = xin[(size_t)p * 4 + 1];
    float cz = xin[(size_t)p * 4 + 2];
    float ct = xin[(size_t)p * 4 + 3];
    float tn = ct / 99.0f;
    float gy = 2.0f * tn - 1.0f;
    float iy = ((gy + 1.0f) * 0.5f) * 99.0f;
    float y0f = floorf(iy);
    float wy1 = iy - y0f;
    float wy0 = 1.0f - wy1;
    int y0 = (int)y0f, y1 = y0 + 1;
    bool y0in = (unsigned)y0 < (unsigned)NFRAMES;
    bool y1in = (unsigned)y1 < (unsigned)NFRAMES;
    int y0c = min(max(y0, 0), NFRAMES - 1);
    int y1c = min(max(y1, 0), NFRAMES - 1);
    float d[3];
    #pragma unroll
    for (int f = 0; f < 3; f++) {
      float prodc;
      #pragma unroll
      for (int pl = 0; pl < 3; pl++) {
        float coord = (pl == 0) ? cx : (pl == 1) ? cy : cz;
        float gx = 2.0f * coord - 1.0f;
        float ix = ((gx + 1.0f) * 0.5f) * 255.0f;
        float x0f = floorf(ix);
        float wx1 = ix - x0f;
        float wx0 = 1.0f - wx1;
        int x0 = (int)x0f, x1 = x0 + 1;
        int x0c = min(max(x0, 0), RESO_ - 1);
        int x1c = min(max(x1, 0), RESO_ - 1);
        const float* ff = (f == 0) ? f0 : (f == 1) ? f1 : f2;
        const float* bse = ff + ((size_t)pl * CHAN_ + lane) * (NFRAMES * RESO_);
        float v00 = y0in ? bse[(size_t)y0c * RESO_ + x0c] : 0.0f;
        float v01 = y0in ? bse[(size_t)y0c * RESO_ + x1c] : 0.0f;
        float v10 = y1in ? bse[(size_t)y1c * RESO_ + x0c] : 0.0f;
        float v11 = y1in ? bse[(size_t)y1c * RESO_ + x1c] : 0.0f;
        float ss2 = v00 * (wy0 * wx0) + v01 * (wy0 * wx1) + v10 * (wy1 * wx0) + v11 * (wy1 * wx1);
        prodc = (pl == 0) ? ss2 : prodc * ss2;
      }
      float sum = prodc;
      #pragma unroll
      for (int o = 32; o > 0; o >>= 1) sum += __shfl_xor(sum, o, 64);
      d[f] = sum;
    }
    float p0 = cx + d[0], p1 = cy + d[1], p2 = cz + d[2];
    if (lane < 63) {
      float val;
      if (lane == 0) val = p0;
      else if (lane == 1) val = p1;
      else if (lane == 2) val = p2;
      else {
        int jj = lane - 3;
        int fq2 = jj / 6;
        int r2 = jj - fq2 * 6;
        int s2 = r2 / 3;
        int d2 = r2 - s2 * 3;
        float pd = (d2 == 0) ? p0 : (d2 == 1) ? p1 : p2;
        float ang = pd * (float)(1 << fq2);
        val = (s2 == 0) ? sinf(ang) : cosf(ang);
      }
      out[(size_t)p * 63 + lane] = val;
    }
  }
}

extern "C" void kernel_launch(void* const* d_in, const int* in_sizes, int n_in,
                              void* d_out, int out_size, void* d_ws, size_t ws_size,
                              hipStream_t stream) {
  const float* x  = (const float*)d_in[0];
  const float* f0 = (const float*)d_in[1];
  const float* f1 = (const float*)d_in[2];
  const float* f2 = (const float*)d_in[3];
  float* out = (float*)d_out;

  const size_t szT2   = (size_t)9 * T2PLANE_B;                  // ~29.5 MB
  const size_t szT    = (size_t)9 * TPLANE * sizeof(float);     // ~59 MB
  const size_t szPerm = (size_t)P_N * sizeof(int);              // 2 MB
  const size_t szXs   = (size_t)P_N * sizeof(float4);           // 8 MB

  if (ws_size >= szT2 + szPerm + szXs) {
    _Float16* T2 = (_Float16*)d_ws;
    int* perm    = (int*)((char*)d_ws + szT2);
    float4* xs4  = (float4*)((char*)d_ws + szT2 + szPerm);
    prep5_k<_Float16, true><<<dim3(NSUBS + NTRB), dim3(256), 0, stream>>>(
        f0, f1, f2, T2, x, perm, xs4);
    sample8h_k<<<dim3(4096), dim3(256), 0, stream>>>(xs4, T2, perm, out);
  } else if (ws_size >= szT) {
    float* T = (float*)d_ws;
    prep5_k<float, false><<<dim3(NSUBS + NTRB), dim3(256), 0, stream>>>(
        f0, f1, f2, T, x, nullptr, nullptr);
    sample2_k<<<dim3(4096), dim3(256), 0, stream>>>(x, T, out);
  } else {
    sample_fb_k<<<dim3(8192), dim3(256), 0, stream>>>(x, f0, f1, f2, out);
  }
}